// Round 2
// baseline (841.393 us; speedup 1.0000x reference)
//
#include <hip/hip_runtime.h>
#include <hip/hip_bf16.h>

#define NB 512
#define NF 8
#define NOUT 32

__device__ __forceinline__ float bf_lo(unsigned u){
  union { unsigned u; float f; } c; c.u = u << 16; return c.f;
}
__device__ __forceinline__ float bf_hi(unsigned u){
  union { unsigned u; float f; } c; c.u = u & 0xffff0000u; return c.f;
}
__device__ __forceinline__ float bf1(unsigned short s){
  union { unsigned u; float f; } c; c.u = ((unsigned)s) << 16; return c.f;
}
__device__ __forceinline__ unsigned short f_to_bf(float f){
  union { float f; unsigned u; } c; c.f = f;
  unsigned r = c.u + 0x7fffu + ((c.u >> 16) & 1u);  // RNE
  return (unsigned short)(r >> 16);
}

__device__ __forceinline__ float wred_max(float v){
#pragma unroll
  for (int o = 32; o > 0; o >>= 1) v = fmaxf(v, __shfl_xor(v, o, 64));
  return v;
}
__device__ __forceinline__ float wred_sum(float v){
#pragma unroll
  for (int o = 32; o > 0; o >>= 1) v += __shfl_xor(v, o, 64);
  return v;
}

// Dtype sniffing: fp32 data has exponents ~[102,135]; bf16 pairs reinterpreted
// as fp32 put bf16 exponent bits into the fp32 exponent byte -> |x|>1e36/NaN.
// int32 masks are strictly {0,1}; byte-packed bools read as int32 exceed 1
// with p=7/8 per word. One wave of samples decides both deterministically.
__global__ void detect_dtypes(const void* __restrict__ ego,
                              const void* __restrict__ mask,
                              int* __restrict__ flags) {
  const int t = threadIdx.x;  // 64 threads
  const float x = ((const float*)ego)[t];
  const int bad_f = (x != x) || (fabsf(x) > 1e30f);
  const unsigned long long vb = __ballot(bad_f);
  const unsigned mv = (unsigned)((const int*)mask)[t];
  const unsigned long long mb = __ballot(mv > 1u);
  if (t == 0) { flags[0] = (vb != 0ull); flags[1] = (mb != 0ull); }
}

// One block per row b. 256 threads; thread t owns neighbors t and t+256.
// Single pass: features stay in registers between score and aggregation.
__global__ __launch_bounds__(256)
void gat_fused(const void* __restrict__ ego,     // B x F
               const void* __restrict__ nbr,     // B x N x F
               const void* __restrict__ mask,    // B x N
               const void* __restrict__ W_ego,   // F x F
               const void* __restrict__ b_ego,   // F
               const void* __restrict__ w_attn,  // 2F
               const void* __restrict__ b_attn,  // 1
               const void* __restrict__ W_out,   // F x OUT
               const void* __restrict__ b_out,   // OUT
               void* __restrict__ out,           // B x OUT
               const int* __restrict__ flags)
{
  const int b = blockIdx.x;
  const int t = threadIdx.x;
  const int lane = t & 63;
  const int wid  = t >> 6;

  const bool isbf   = flags[0] != 0;
  const bool mbytes = flags[1] != 0;

  __shared__ float redA[4];
  __shared__ float redB[4];
  __shared__ float agg[4][NF];

  // scalar weight load honoring dtype flag (tiny, L2-resident)
  auto ldw = [&](const void* p, int i) -> float {
    return isbf ? bf1(((const unsigned short*)p)[i]) : ((const float*)p)[i];
  };

  float wa_n[NF];
#pragma unroll
  for (int j = 0; j < NF; ++j) wa_n[j] = ldw(w_attn, NF + j);

  // s_e = (ego[b] @ W_ego + b_ego) . wa_e + b_attn  (uniform per block)
  float s_e = ldw(b_attn, 0);
  {
    float e[NF];
#pragma unroll
    for (int i = 0; i < NF; ++i) e[i] = ldw(ego, b * NF + i);
#pragma unroll
    for (int j = 0; j < NF; ++j) {
      float p = ldw(b_ego, j);
#pragma unroll
      for (int i = 0; i < NF; ++i) p = fmaf(e[i], ldw(W_ego, i * NF + j), p);
      s_e = fmaf(p, ldw(w_attn, j), s_e);
    }
  }

  const int n0 = t, n1 = t + 256;
  float v0[NF], v1[NF];
  if (isbf) {
    const uint4* row = reinterpret_cast<const uint4*>(nbr) + (size_t)b * NB;
    const uint4 p0 = row[n0];
    const uint4 p1 = row[n1];
    v0[0]=bf_lo(p0.x); v0[1]=bf_hi(p0.x); v0[2]=bf_lo(p0.y); v0[3]=bf_hi(p0.y);
    v0[4]=bf_lo(p0.z); v0[5]=bf_hi(p0.z); v0[6]=bf_lo(p0.w); v0[7]=bf_hi(p0.w);
    v1[0]=bf_lo(p1.x); v1[1]=bf_hi(p1.x); v1[2]=bf_lo(p1.y); v1[3]=bf_hi(p1.y);
    v1[4]=bf_lo(p1.z); v1[5]=bf_hi(p1.z); v1[6]=bf_lo(p1.w); v1[7]=bf_hi(p1.w);
  } else {
    const float4* row = reinterpret_cast<const float4*>(nbr) + (size_t)b * NB * 2;
    const float4 q0 = row[2*n0], q1 = row[2*n0+1];
    const float4 q2 = row[2*n1], q3 = row[2*n1+1];
    v0[0]=q0.x; v0[1]=q0.y; v0[2]=q0.z; v0[3]=q0.w;
    v0[4]=q1.x; v0[5]=q1.y; v0[6]=q1.z; v0[7]=q1.w;
    v1[0]=q2.x; v1[1]=q2.y; v1[2]=q2.z; v1[3]=q2.w;
    v1[4]=q3.x; v1[5]=q3.y; v1[6]=q3.z; v1[7]=q3.w;
  }

  int m0, m1;
  if (mbytes) {
    const unsigned char* mp = (const unsigned char*)mask + (size_t)b * NB;
    m0 = mp[n0] != 0; m1 = mp[n1] != 0;
  } else {
    const int* mp = (const int*)mask + (size_t)b * NB;
    m0 = mp[n0] != 0; m1 = mp[n1] != 0;
  }

  float s0 = s_e, s1 = s_e;
#pragma unroll
  for (int i = 0; i < NF; ++i) {
    s0 = fmaf(v0[i], wa_n[i], s0);
    s1 = fmaf(v1[i], wa_n[i], s1);
  }
  // all-masked special case in the reference is output-equivalent to this
  // (-1e9 everywhere -> e=1 -> weights*mask=0 -> out=b_out), so no branch.
  const float ms0 = m0 ? s0 : -1e9f;
  const float ms1 = m1 ? s1 : -1e9f;

  float mx = wred_max(fmaxf(ms0, ms1));
  if (lane == 0) redA[wid] = mx;
  __syncthreads();
  mx = fmaxf(fmaxf(redA[0], redA[1]), fmaxf(redA[2], redA[3]));

  const float e0 = __expf(ms0 - mx);
  const float e1 = __expf(ms1 - mx);
  float sm = wred_sum(e0 + e1);
  if (lane == 0) redB[wid] = sm;
  __syncthreads();
  sm = (redB[0] + redB[1]) + (redB[2] + redB[3]);
  const float inv = 1.0f / sm;   // sm >= 1 (max lane contributes exp(0)=1)

  const float w0 = e0 * inv * (float)m0;
  const float w1 = e1 * inv * (float)m1;

  float a[NF];
#pragma unroll
  for (int i = 0; i < NF; ++i) a[i] = w0 * v0[i] + w1 * v1[i];
#pragma unroll
  for (int i = 0; i < NF; ++i) a[i] = wred_sum(a[i]);
  if (lane == 0) {
#pragma unroll
    for (int i = 0; i < NF; ++i) agg[wid][i] = a[i];
  }
  __syncthreads();

  if (t < NOUT) {
    float o = ldw(b_out, t);
#pragma unroll
    for (int f = 0; f < NF; ++f) {
      const float ag = (agg[0][f] + agg[1][f]) + (agg[2][f] + agg[3][f]);
      o = fmaf(ag, ldw(W_out, f * NOUT + t), o);
    }
    if (isbf) ((unsigned short*)out)[(size_t)b * NOUT + t] = f_to_bf(o);
    else      ((float*)out)[(size_t)b * NOUT + t] = o;
  }
}

extern "C" void kernel_launch(void* const* d_in, const int* in_sizes, int n_in,
                              void* d_out, int out_size, void* d_ws, size_t ws_size,
                              hipStream_t stream) {
  int* flags = (int*)d_ws;
  detect_dtypes<<<1, 64, 0, stream>>>(d_in[0], d_in[2], flags);

  const int Bn = in_sizes[0] / NF;  // 32768 rows
  gat_fused<<<Bn, 256, 0, stream>>>(d_in[0], d_in[1], d_in[2], d_in[3], d_in[4],
                                    d_in[5], d_in[6], d_in[7], d_in[8],
                                    d_out, flags);
}